// Round 1
// baseline (206.653 us; speedup 1.0000x reference)
//
#include <hip/hip_runtime.h>
#include <stdint.h>

typedef _Float16 f16;
typedef f16 f16x8 __attribute__((ext_vector_type(8)));
typedef float f32x4 __attribute__((ext_vector_type(4)));

#define AS1 __attribute__((address_space(1)))
#define AS3 __attribute__((address_space(3)))

// async global->LDS, 16B per lane. LDS dest is wave-uniform base + lane*16.
__device__ __forceinline__ void gll16(const void* g, void* l) {
  __builtin_amdgcn_global_load_lds((AS1 void*)g, (AS3 void*)l, 16, 0, 0);
}

__device__ __forceinline__ f32x4 mfma16(f16x8 a, f16x8 b, f32x4 c) {
  return __builtin_amdgcn_mfma_f32_16x16x32_f16(a, b, c, 0, 0, 0);
}

// ---------------- pack kernels ----------------

__global__ __launch_bounds__(256) void pack_x_k(const float* __restrict__ x,
                                                f16* __restrict__ xh, int n) {
  int i = (blockIdx.x * 256 + threadIdx.x) * 8;
  if (i < n) {
    float4 a = *(const float4*)(x + i);
    float4 b = *(const float4*)(x + i + 4);
    f16x8 o;
    o[0] = (f16)a.x; o[1] = (f16)a.y; o[2] = (f16)a.z; o[3] = (f16)a.w;
    o[4] = (f16)b.x; o[5] = (f16)b.y; o[6] = (f16)b.z; o[7] = (f16)b.w;
    *(f16x8*)(xh + i) = o;
  }
}

// Transpose+convert one 64x64 tile of W[k][n] (f32) -> Wt[n][k] (f16).
// z selects matrix: 0=Wq 1=Wk 2=Wv 3=Wo; dst rows offset by z*1024.
__global__ __launch_bounds__(256) void pack_w_k(const float* __restrict__ Wq,
                                                const float* __restrict__ Wk,
                                                const float* __restrict__ Wv,
                                                const float* __restrict__ Wo,
                                                f16* __restrict__ Wt) {
  __shared__ f16 t[64][65];
  const float* W = (blockIdx.z == 0) ? Wq : (blockIdx.z == 1) ? Wk
                   : (blockIdx.z == 2) ? Wv : Wo;
  int n0 = blockIdx.x * 64, k0 = blockIdx.y * 64;
  int tid = threadIdx.x;
  int kr = tid >> 4;         // 0..15
  int nc = (tid & 15) * 4;   // 0..60
#pragma unroll
  for (int i = 0; i < 4; i++) {
    int k = k0 + kr + i * 16;
    float4 w = *(const float4*)(W + (size_t)k * 1024 + n0 + nc);
    t[nc + 0][kr + i * 16] = (f16)w.x;
    t[nc + 1][kr + i * 16] = (f16)w.y;
    t[nc + 2][kr + i * 16] = (f16)w.z;
    t[nc + 3][kr + i * 16] = (f16)w.w;
  }
  __syncthreads();
  int nr = tid >> 2;          // 0..63
  int c0 = (tid & 3) * 16;    // 0..48
  alignas(16) f16 tmp[16];
#pragma unroll
  for (int e = 0; e < 16; e++) tmp[e] = t[nr][c0 + e];
  f16* dst = Wt + (size_t)(blockIdx.z * 1024 + n0 + nr) * 1024 + k0 + c0;
  *(f16x8*)(dst) = *(const f16x8*)(tmp);
  *(f16x8*)(dst + 8) = *(const f16x8*)(tmp + 8);
}

// ---------------- GEMM mainloop (128x128 tile, BK=64, f16 MFMA) ----------------
// A: [M][1024] f16 row-major; B: [N][1024] f16 row-major (i.e. W^T).
// LDS tiles [128 rows][64 cols f16] = 128B rows, XOR-swizzled at 16B granules:
// byte(row, colb) = row*128 + (colb ^ ((row&7)<<4)). Staged via global_load_lds
// with the inverse swizzle applied to the GLOBAL source address (rule #21).
__device__ __forceinline__ void gemm_main(const f16* __restrict__ A,
                                          const f16* __restrict__ B,
                                          int m0, int n0,
                                          f16* Al, f16* Bl,
                                          f32x4 acc[4][4]) {
  const int K = 1024;
  int tid = threadIdx.x;
  int lane = tid & 63, wid = tid >> 6;
  int wr = (wid >> 1) * 64, wc = (wid & 1) * 64;
#pragma unroll
  for (int mi = 0; mi < 4; mi++)
#pragma unroll
    for (int nj = 0; nj < 4; nj++) {
      f32x4 z = {0.f, 0.f, 0.f, 0.f};
      acc[mi][nj] = z;
    }
  int srow = lane >> 3;            // row within 8-row chunk
  int sgr = (lane & 7) ^ srow;     // pre-swizzled source granule
  int lr = lane & 15, lg = lane >> 4;
  for (int kt = 0; kt < 16; ++kt) {
    __syncthreads();
#pragma unroll
    for (int q = 0; q < 4; q++) {
      int chunk = wid * 4 + q;     // 0..15 (1KB chunks)
      int row = chunk * 8 + srow;  // 0..127
      gll16(A + (size_t)(m0 + row) * K + kt * 64 + sgr * 8, Al + chunk * 512);
      gll16(B + (size_t)(n0 + row) * K + kt * 64 + sgr * 8, Bl + chunk * 512);
    }
    __syncthreads();
#pragma unroll
    for (int kk = 0; kk < 2; kk++) {
      f16x8 af[4], bf[4];
#pragma unroll
      for (int mi = 0; mi < 4; mi++) {
        int row = wr + mi * 16 + lr;
        int gr = (kk * 4 + lg) ^ (row & 7);
        af[mi] = *(const f16x8*)(Al + row * 64 + gr * 8);
      }
#pragma unroll
      for (int nj = 0; nj < 4; nj++) {
        int row = wc + nj * 16 + lr;
        int gr = (kk * 4 + lg) ^ (row & 7);
        bf[nj] = *(const f16x8*)(Bl + row * 64 + gr * 8);
      }
#pragma unroll
      for (int mi = 0; mi < 4; mi++)
#pragma unroll
        for (int nj = 0; nj < 4; nj++)
          acc[mi][nj] = mfma16(af[mi], bf[nj], acc[mi][nj]);
    }
  }
}

// Stage 1: [4096,1024] @ [1024,3072] -> Q,K,V f16 [bh=32][s=2048][d=64].
// Q gets the 1/sqrt(64) scale folded in.
__global__ __launch_bounds__(256) void gemm_qkv_k(const f16* __restrict__ Xh,
                                                  const f16* __restrict__ Wt,
                                                  const float* __restrict__ bq,
                                                  const float* __restrict__ bk,
                                                  const float* __restrict__ bv,
                                                  f16* __restrict__ Q,
                                                  f16* __restrict__ Kb,
                                                  f16* __restrict__ V) {
  __shared__ f16 Al[128 * 64];
  __shared__ f16 Bl[128 * 64];
  f32x4 acc[4][4];
  int m0 = blockIdx.y * 128, n0 = blockIdx.x * 128;
  gemm_main(Xh, Wt, m0, n0, Al, Bl, acc);

  int lane = threadIdx.x & 63, wid = threadIdx.x >> 6;
  int wr = (wid >> 1) * 64, wc = (wid & 1) * 64;
  int lg = lane >> 4, lc = lane & 15;
  int which = n0 >> 10;  // 0=q 1=k 2=v (block-uniform; tiles never straddle)
  const float* bias = (which == 0) ? bq : (which == 1) ? bk : bv;
  f16* out = (which == 0) ? Q : (which == 1) ? Kb : V;
  float scale = (which == 0) ? 0.125f : 1.0f;
#pragma unroll
  for (int mi = 0; mi < 4; mi++)
#pragma unroll
    for (int nj = 0; nj < 4; nj++) {
      int n = n0 + wc + nj * 16 + lc;
      int nh = n & 1023;
      int h = nh >> 6, d = nh & 63;
      float bb = bias[nh];
#pragma unroll
      for (int r = 0; r < 4; r++) {
        int m = m0 + wr + mi * 16 + lg * 4 + r;
        int b = m >> 11, s = m & 2047;
        float v = (acc[mi][nj][r] + bb) * scale;
        out[((size_t)(b * 16 + h) * 2048 + s) * 64 + d] = (f16)v;
      }
    }
}

// Stage 3: Oh[4096,1024] @ Wo -> d_out (f32) + bo.
__global__ __launch_bounds__(256) void gemm_out_k(const f16* __restrict__ Oh,
                                                  const f16* __restrict__ Wt,
                                                  const float* __restrict__ bo,
                                                  float* __restrict__ out) {
  __shared__ f16 Al[128 * 64];
  __shared__ f16 Bl[128 * 64];
  f32x4 acc[4][4];
  int m0 = blockIdx.y * 128, n0 = blockIdx.x * 128;
  gemm_main(Oh, Wt, m0, n0, Al, Bl, acc);

  int lane = threadIdx.x & 63, wid = threadIdx.x >> 6;
  int wr = (wid >> 1) * 64, wc = (wid & 1) * 64;
  int lg = lane >> 4, lc = lane & 15;
#pragma unroll
  for (int mi = 0; mi < 4; mi++)
#pragma unroll
    for (int nj = 0; nj < 4; nj++) {
      int n = n0 + wc + nj * 16 + lc;
      float bb = bo[n];
#pragma unroll
      for (int r = 0; r < 4; r++) {
        int m = m0 + wr + mi * 16 + lg * 4 + r;
        out[(size_t)m * 1024 + n] = acc[mi][nj][r] + bb;
      }
    }
}

// ---------------- flash attention ----------------
// grid (32 q-blocks, 32 bh). 4 waves x 16 q-rows. Q scaled by 1/8 already.
// Scores S[q][kv] via mfma(Q,K) (lane: row q=4g+r, col kv=c). Online softmax
// fully in-register via __shfl_xor over the 16-lane column group. P round-trips
// through per-wave LDS to reach the MFMA A-operand layout.
__global__ __launch_bounds__(256) void attn_k(const f16* __restrict__ Q,
                                              const f16* __restrict__ K,
                                              const f16* __restrict__ V,
                                              f16* __restrict__ Oh) {
  __shared__ f16 Klds[64 * 64];       // [kv][d], swizzled rows of 128B
  __shared__ f16 Vt[64 * 64];         // [d][kv], swizzled
  __shared__ f16 Plds[4 * 16 * 64];   // per-wave [16 q][64 kv], swizzled

  int tid = threadIdx.x, lane = tid & 63, wid = tid >> 6;
  int lg = lane >> 4, lc = lane & 15;
  int bh = blockIdx.y;
  int q0 = blockIdx.x * 64 + wid * 16;
  const f16* Qp = Q + (size_t)bh * 2048 * 64;
  const f16* Kp = K + (size_t)bh * 2048 * 64;
  const f16* Vp = V + (size_t)bh * 2048 * 64;

  // Q A-fragments in registers (row = lane&15, k = 32*kc + 8*(lane>>4)+j)
  f16x8 qf[2];
#pragma unroll
  for (int kc = 0; kc < 2; kc++)
    qf[kc] = *(const f16x8*)(Qp + (size_t)(q0 + lc) * 64 + kc * 32 + lg * 8);

  f32x4 accO[4];
#pragma unroll
  for (int db = 0; db < 4; db++) {
    f32x4 z = {0.f, 0.f, 0.f, 0.f};
    accO[db] = z;
  }
  float m[4], l[4];
#pragma unroll
  for (int r = 0; r < 4; r++) { m[r] = -1e30f; l[r] = 0.f; }

  int srow = lane >> 3;
  int sgr = (lane & 7) ^ srow;
  int vkv = tid >> 2, vc0 = (tid & 3) * 16;
  f16* Pw = Plds + wid * 1024;

  for (int t0 = 0; t0 < 2048; t0 += 64) {
    __syncthreads();
    // stage K tile (8KB = 8 chunks, 2 per wave) via global_load_lds
#pragma unroll
    for (int q = 0; q < 2; q++) {
      int chunk = wid * 2 + q;
      int row = chunk * 8 + srow;
      gll16(Kp + (size_t)(t0 + row) * 64 + sgr * 8, Klds + chunk * 512);
    }
    // stage V^T (scalar transpose writes, swizzled)
    {
      const f16* vsrc = Vp + (size_t)(t0 + vkv) * 64 + vc0;
      f16x8 v0 = *(const f16x8*)(vsrc);
      f16x8 v1 = *(const f16x8*)(vsrc + 8);
      int kvg = vkv >> 3, kvo = vkv & 7;
#pragma unroll
      for (int e = 0; e < 8; e++) {
        int d0 = vc0 + e;
        Vt[d0 * 64 + ((kvg ^ (d0 & 7)) << 3) + kvo] = v0[e];
        int d1 = vc0 + 8 + e;
        Vt[d1 * 64 + ((kvg ^ (d1 & 7)) << 3) + kvo] = v1[e];
      }
    }
    __syncthreads();

    // QK^T: 16 q-rows x 64 kv
    f32x4 sf[4];
#pragma unroll
    for (int nf = 0; nf < 4; nf++) {
      f32x4 z = {0.f, 0.f, 0.f, 0.f};
#pragma unroll
      for (int kc = 0; kc < 2; kc++) {
        int row = nf * 16 + lc;
        int gr = (kc * 4 + lg) ^ (row & 7);
        f16x8 kf = *(const f16x8*)(Klds + row * 64 + gr * 8);
        z = mfma16(qf[kc], kf, z);
      }
      sf[nf] = z;
    }

    // online softmax (rows 4*lg+r live in the 16-lane group)
    float tm[4];
#pragma unroll
    for (int r = 0; r < 4; r++)
      tm[r] = fmaxf(fmaxf(sf[0][r], sf[1][r]), fmaxf(sf[2][r], sf[3][r]));
#pragma unroll
    for (int r = 0; r < 4; r++) {
      tm[r] = fmaxf(tm[r], __shfl_xor(tm[r], 1, 64));
      tm[r] = fmaxf(tm[r], __shfl_xor(tm[r], 2, 64));
      tm[r] = fmaxf(tm[r], __shfl_xor(tm[r], 4, 64));
      tm[r] = fmaxf(tm[r], __shfl_xor(tm[r], 8, 64));
    }
    float ts[4];
#pragma unroll
    for (int r = 0; r < 4; r++) {
      float nm = fmaxf(m[r], tm[r]);
      float al = __expf(m[r] - nm);
      m[r] = nm;
      l[r] *= al;
      ts[r] = 0.f;
#pragma unroll
      for (int db = 0; db < 4; db++) accO[db][r] *= al;
    }
#pragma unroll
    for (int nf = 0; nf < 4; nf++)
#pragma unroll
      for (int r = 0; r < 4; r++) {
        float p = __expf(sf[nf][r] - m[r]);
        sf[nf][r] = p;
        ts[r] += p;
      }
#pragma unroll
    for (int r = 0; r < 4; r++) {
      ts[r] += __shfl_xor(ts[r], 1, 64);
      ts[r] += __shfl_xor(ts[r], 2, 64);
      ts[r] += __shfl_xor(ts[r], 4, 64);
      ts[r] += __shfl_xor(ts[r], 8, 64);
      l[r] += ts[r];
    }

    // P -> per-wave LDS (f16, swizzled), then read back as A-fragments
#pragma unroll
    for (int nf = 0; nf < 4; nf++)
#pragma unroll
      for (int r = 0; r < 4; r++) {
        int row = lg * 4 + r;
        Pw[row * 64 + (((2 * nf + (lc >> 3)) ^ (row & 7)) << 3) + (lc & 7)] =
            (f16)sf[nf][r];
      }

    // PV: O[16 q][64 d] += P(16x64) @ V(64x64)
#pragma unroll
    for (int kc = 0; kc < 2; kc++) {
      int pg = (kc * 4 + lg) ^ (lc & 7);
      f16x8 pf = *(const f16x8*)(Pw + lc * 64 + pg * 8);
#pragma unroll
      for (int db = 0; db < 4; db++) {
        int vrow = db * 16 + lc;
        int vg = (kc * 4 + lg) ^ (vrow & 7);
        f16x8 vf = *(const f16x8*)(Vt + vrow * 64 + vg * 8);
        accO[db] = mfma16(pf, vf, accO[db]);
      }
    }
  }

  // epilogue: normalize and store Oh[b*2048+s][h*64+d] (f16)
  int b = bh >> 4, h = bh & 15;
#pragma unroll
  for (int db = 0; db < 4; db++)
#pragma unroll
    for (int r = 0; r < 4; r++) {
      int s = q0 + lg * 4 + r;
      float ov = accO[db][r] / l[r];
      Oh[((size_t)(b * 2048 + s)) * 1024 + h * 64 + db * 16 + lc] = (f16)ov;
    }
}

// ---------------- launch ----------------

extern "C" void kernel_launch(void* const* d_in, const int* in_sizes, int n_in,
                              void* d_out, int out_size, void* d_ws, size_t ws_size,
                              hipStream_t stream) {
  const float* x  = (const float*)d_in[0];
  const float* Wq = (const float*)d_in[1];
  const float* bq = (const float*)d_in[2];
  const float* Wk = (const float*)d_in[3];
  const float* bk = (const float*)d_in[4];
  const float* Wv = (const float*)d_in[5];
  const float* bv = (const float*)d_in[6];
  const float* Wo = (const float*)d_in[7];
  const float* bo = (const float*)d_in[8];
  float* out = (float*)d_out;

  char* ws = (char*)d_ws;
  const size_t MB8 = (size_t)8 << 20;  // 4096*1024 f16
  f16* Xh = (f16*)(ws + 0 * MB8);
  f16* Wt = (f16*)(ws + 1 * MB8);  // rows 0..3071 = Wq^T,Wk^T,Wv^T; 3072.. = Wo^T
  f16* Q  = (f16*)(ws + 2 * MB8);
  f16* Kb = (f16*)(ws + 3 * MB8);
  f16* V  = (f16*)(ws + 4 * MB8);
  f16* Oh = (f16*)(ws + 5 * MB8);

  pack_x_k<<<dim3(2048), dim3(256), 0, stream>>>(x, Xh, 4096 * 1024);
  pack_w_k<<<dim3(16, 16, 4), dim3(256), 0, stream>>>(Wq, Wk, Wv, Wo, Wt);
  gemm_qkv_k<<<dim3(24, 32), dim3(256), 0, stream>>>(Xh, Wt, bq, bk, bv, Q, Kb, V);
  attn_k<<<dim3(32, 32), dim3(256), 0, stream>>>(Q, Kb, V, Oh);
  gemm_out_k<<<dim3(8, 32), dim3(256), 0, stream>>>(Oh, Wt + (size_t)3072 * 1024, bo, out);
}

// Round 3
// 145.323 us; speedup vs baseline: 1.4220x; 1.4220x over previous
//
#include <hip/hip_runtime.h>
#include <stdint.h>

typedef _Float16 f16;
typedef f16 f16x4 __attribute__((ext_vector_type(4)));
typedef f16 f16x8 __attribute__((ext_vector_type(8)));
typedef __fp16 hf16x2 __attribute__((ext_vector_type(2)));
typedef float f32x4 __attribute__((ext_vector_type(4)));
typedef float f32x16 __attribute__((ext_vector_type(16)));

#define AS1 __attribute__((address_space(1)))
#define AS3 __attribute__((address_space(3)))

// async global->LDS, 16B per lane. LDS dest is wave-uniform base + lane*16.
__device__ __forceinline__ void gll16(const void* g, void* l) {
  __builtin_amdgcn_global_load_lds((AS1 void*)g, (AS3 void*)l, 16, 0, 0);
}

__device__ __forceinline__ f32x4 mfma16(f16x8 a, f16x8 b, f32x4 c) {
  return __builtin_amdgcn_mfma_f32_16x16x32_f16(a, b, c, 0, 0, 0);
}
__device__ __forceinline__ f32x16 mfma32(f16x8 a, f16x8 b, f32x16 c) {
  return __builtin_amdgcn_mfma_f32_32x32x16_f16(a, b, c, 0, 0, 0);
}

__device__ __forceinline__ uint32_t pkrtz(float a, float b) {
  union { hf16x2 h; uint32_t u; } c;
  c.h = __builtin_amdgcn_cvt_pkrtz(a, b);
  return c.u;
}

// v_permlane32_swap_b32 D,S : D.hi <-> S.lo  (D'[i+32]=S[i]; S'[i]=D[i+32])
__device__ __forceinline__ void pl32(uint32_t& x, uint32_t& y) {
  asm("v_permlane32_swap_b32 %0, %1" : "+v"(x), "+v"(y));
}

// Build PV B-operand fragment (k-slice of 16 kv rows) from 16 S^T C-regs.
// Lane holds P[crow(r,hi)][q], crow = (r&3)+8*(r>>2)+4*hi. Needed:
// word w = rows (8*hi+2w, 8*hi+2w+1).
__device__ __forceinline__ f16x8 mk_bfrag(float e0, float e1, float e2, float e3,
                                          float e4, float e5, float e6, float e7) {
  uint32_t x0 = pkrtz(e0, e1), y0 = pkrtz(e4, e5);
  uint32_t x1 = pkrtz(e2, e3), y1 = pkrtz(e6, e7);
  pl32(x0, y0);
  pl32(x1, y1);
  union { uint32_t w[4]; f16x8 v; } u;
  u.w[0] = x0; u.w[1] = x1; u.w[2] = y0; u.w[3] = y1;
  return u.v;
}

__device__ __forceinline__ f32x16 zero16() {
  f32x16 z;
#pragma unroll
  for (int i = 0; i < 16; i++) z[i] = 0.f;
  return z;
}

// ---------------- pack kernels ----------------

__global__ __launch_bounds__(256) void pack_x_k(const float* __restrict__ x,
                                                f16* __restrict__ xh, int n) {
  int i = (blockIdx.x * 256 + threadIdx.x) * 8;
  if (i < n) {
    float4 a = *(const float4*)(x + i);
    float4 b = *(const float4*)(x + i + 4);
    f16x8 o;
    o[0] = (f16)a.x; o[1] = (f16)a.y; o[2] = (f16)a.z; o[3] = (f16)a.w;
    o[4] = (f16)b.x; o[5] = (f16)b.y; o[6] = (f16)b.z; o[7] = (f16)b.w;
    *(f16x8*)(xh + i) = o;
  }
}

// Transpose+convert one 64x64 tile of W[k][n] (f32) -> Wt[n][k] (f16).
__global__ __launch_bounds__(256) void pack_w_k(const float* __restrict__ Wq,
                                                const float* __restrict__ Wk,
                                                const float* __restrict__ Wv,
                                                const float* __restrict__ Wo,
                                                f16* __restrict__ Wt) {
  __shared__ f16 t[64][65];
  const float* W = (blockIdx.z == 0) ? Wq : (blockIdx.z == 1) ? Wk
                   : (blockIdx.z == 2) ? Wv : Wo;
  int n0 = blockIdx.x * 64, k0 = blockIdx.y * 64;
  int tid = threadIdx.x;
  int kr = tid >> 4;
  int nc = (tid & 15) * 4;
#pragma unroll
  for (int i = 0; i < 4; i++) {
    int k = k0 + kr + i * 16;
    float4 w = *(const float4*)(W + (size_t)k * 1024 + n0 + nc);
    t[nc + 0][kr + i * 16] = (f16)w.x;
    t[nc + 1][kr + i * 16] = (f16)w.y;
    t[nc + 2][kr + i * 16] = (f16)w.z;
    t[nc + 3][kr + i * 16] = (f16)w.w;
  }
  __syncthreads();
  int nr = tid >> 2;
  int c0 = (tid & 3) * 16;
  alignas(16) f16 tmp[16];
#pragma unroll
  for (int e = 0; e < 16; e++) tmp[e] = t[nr][c0 + e];
  f16* dst = Wt + (size_t)(blockIdx.z * 1024 + n0 + nr) * 1024 + k0 + c0;
  *(f16x8*)(dst) = *(const f16x8*)(tmp);
  *(f16x8*)(dst + 8) = *(const f16x8*)(tmp + 8);
}

// ---------------- GEMM mainloop (128x128 tile, BK=64, f16 MFMA) ----------------
__device__ __forceinline__ void gemm_main(const f16* __restrict__ A,
                                          const f16* __restrict__ B,
                                          int m0, int n0,
                                          f16* Al, f16* Bl,
                                          f32x4 acc[4][4]) {
  const int K = 1024;
  int tid = threadIdx.x;
  int lane = tid & 63, wid = tid >> 6;
  int wr = (wid >> 1) * 64, wc = (wid & 1) * 64;
#pragma unroll
  for (int mi = 0; mi < 4; mi++)
#pragma unroll
    for (int nj = 0; nj < 4; nj++) {
      f32x4 z = {0.f, 0.f, 0.f, 0.f};
      acc[mi][nj] = z;
    }
  int srow = lane >> 3;
  int sgr = (lane & 7) ^ srow;
  int lr = lane & 15, lg = lane >> 4;
  for (int kt = 0; kt < 16; ++kt) {
    __syncthreads();
#pragma unroll
    for (int q = 0; q < 4; q++) {
      int chunk = wid * 4 + q;
      int row = chunk * 8 + srow;
      gll16(A + (size_t)(m0 + row) * K + kt * 64 + sgr * 8, Al + chunk * 512);
      gll16(B + (size_t)(n0 + row) * K + kt * 64 + sgr * 8, Bl + chunk * 512);
    }
    __syncthreads();
#pragma unroll
    for (int kk = 0; kk < 2; kk++) {
      f16x8 af[4], bf[4];
#pragma unroll
      for (int mi = 0; mi < 4; mi++) {
        int row = wr + mi * 16 + lr;
        int gr = (kk * 4 + lg) ^ (row & 7);
        af[mi] = *(const f16x8*)(Al + row * 64 + gr * 8);
      }
#pragma unroll
      for (int nj = 0; nj < 4; nj++) {
        int row = wc + nj * 16 + lr;
        int gr = (kk * 4 + lg) ^ (row & 7);
        bf[nj] = *(const f16x8*)(Bl + row * 64 + gr * 8);
      }
#pragma unroll
      for (int mi = 0; mi < 4; mi++)
#pragma unroll
        for (int nj = 0; nj < 4; nj++)
          acc[mi][nj] = mfma16(af[mi], bf[nj], acc[mi][nj]);
    }
  }
}

// Stage 1: QKV projections. Q,K -> [bh][s][64] f16 (Q scaled by 1/8);
// V -> TRANSPOSED [bh][d=64][s=2048] f16 for the attention PV A-operand.
__global__ __launch_bounds__(256) void gemm_qkv_k(const f16* __restrict__ Xh,
                                                  const f16* __restrict__ Wt,
                                                  const float* __restrict__ bq,
                                                  const float* __restrict__ bk,
                                                  const float* __restrict__ bv,
                                                  f16* __restrict__ Q,
                                                  f16* __restrict__ Kb,
                                                  f16* __restrict__ Vt) {
  __shared__ f16 Al[128 * 64];
  __shared__ f16 Bl[128 * 64];
  f32x4 acc[4][4];
  int m0 = blockIdx.y * 128, n0 = blockIdx.x * 128;
  gemm_main(Xh, Wt, m0, n0, Al, Bl, acc);

  int lane = threadIdx.x & 63, wid = threadIdx.x >> 6;
  int wr = (wid >> 1) * 64, wc = (wid & 1) * 64;
  int lg = lane >> 4, lc = lane & 15;
  int which = n0 >> 10;  // 0=q 1=k 2=v
  if (which == 2) {
#pragma unroll
    for (int mi = 0; mi < 4; mi++)
#pragma unroll
      for (int nj = 0; nj < 4; nj++) {
        int nh = (n0 + wc + nj * 16 + lc) & 1023;
        int h = nh >> 6, d = nh & 63;
        float bb = bv[nh];
        int mbase = m0 + wr + mi * 16 + lg * 4;
        int b = mbase >> 11, s = mbase & 2047;
        f16x4 vv;
#pragma unroll
        for (int r = 0; r < 4; r++) vv[r] = (f16)(acc[mi][nj][r] + bb);
        *(f16x4*)(Vt + ((size_t)(b * 16 + h) * 64 + d) * 2048 + s) = vv;
      }
  } else {
    const float* bias = (which == 0) ? bq : bk;
    f16* out = (which == 0) ? Q : Kb;
    float scale = (which == 0) ? 0.125f : 1.0f;
#pragma unroll
    for (int mi = 0; mi < 4; mi++)
#pragma unroll
      for (int nj = 0; nj < 4; nj++) {
        int nh = (n0 + wc + nj * 16 + lc) & 1023;
        int h = nh >> 6, d = nh & 63;
        float bb = bias[nh];
#pragma unroll
        for (int r = 0; r < 4; r++) {
          int m = m0 + wr + mi * 16 + lg * 4 + r;
          int b = m >> 11, s = m & 2047;
          float v = (acc[mi][nj][r] + bb) * scale;
          out[((size_t)(b * 16 + h) * 2048 + s) * 64 + d] = (f16)v;
        }
      }
  }
}

// Stage 3: Oh[4096,1024] @ Wo -> d_out (f32) + bo.
__global__ __launch_bounds__(256) void gemm_out_k(const f16* __restrict__ Oh,
                                                  const f16* __restrict__ Wt,
                                                  const float* __restrict__ bo,
                                                  float* __restrict__ out) {
  __shared__ f16 Al[128 * 64];
  __shared__ f16 Bl[128 * 64];
  f32x4 acc[4][4];
  int m0 = blockIdx.y * 128, n0 = blockIdx.x * 128;
  gemm_main(Oh, Wt, m0, n0, Al, Bl, acc);

  int lane = threadIdx.x & 63, wid = threadIdx.x >> 6;
  int wr = (wid >> 1) * 64, wc = (wid & 1) * 64;
  int lg = lane >> 4, lc = lane & 15;
#pragma unroll
  for (int mi = 0; mi < 4; mi++)
#pragma unroll
    for (int nj = 0; nj < 4; nj++) {
      int n = n0 + wc + nj * 16 + lc;
      float bb = bo[n];
#pragma unroll
      for (int r = 0; r < 4; r++) {
        int m = m0 + wr + mi * 16 + lg * 4 + r;
        out[(size_t)m * 1024 + n] = acc[mi][nj][r] + bb;
      }
    }
}

// ---------------- flash attention (swapped-operand, 32x32x16) ----------------
// Grid 1024 blocks x 128 thr (2 waves); wave owns 32 q-rows. Per KV-64 tile:
// S^T = mfma(K, Q)  (lane = one q-column, 16 kv rows per 32-tile half),
// lane-local online softmax (+1 shfl_xor(32)), P -> B-frags in-register via
// cvt_pkrtz + permlane32_swap, O^T += mfma(V^T, P). K and V^T staged via
// global_load_lds (linear dest, pre-swizzled source), double-buffered with
// counted vmcnt(8) + raw s_barrier.
__global__ __launch_bounds__(128) void attn_k(const f16* __restrict__ Q,
                                              const f16* __restrict__ K,
                                              const f16* __restrict__ Vt,
                                              f16* __restrict__ Oh) {
  __shared__ alignas(16) f16 Kl[2][64 * 64];
  __shared__ alignas(16) f16 Vl[2][64 * 64];

  int tid = threadIdx.x, lane = tid & 63, wid = tid >> 6;
  int q5 = lane & 31, hi = lane >> 5;
  // XCD swizzle: blocks of one bh land on one XCD (id%8 = bh&7 assumed RR).
  int b0 = blockIdx.x;
  int qc = (b0 >> 3) & 31;
  int bh = (b0 & 7) + ((b0 >> 8) << 3);
  int q0w = qc * 64 + wid * 32;

  const f16* Qp = Q + (size_t)bh * 2048 * 64;
  const f16* Kp = K + (size_t)bh * 2048 * 64;
  const f16* Vp = Vt + (size_t)bh * 64 * 2048;

  // Q B-operand fragments: B[k=d][col=q], lane holds q=lane&31, d=16ks+8hi+j
  f16x8 qf0, qf1, qf2, qf3;
  {
    const f16* qr = Qp + (size_t)(q0w + q5) * 64 + hi * 8;
    qf0 = *(const f16x8*)(qr);
    qf1 = *(const f16x8*)(qr + 16);
    qf2 = *(const f16x8*)(qr + 32);
    qf3 = *(const f16x8*)(qr + 48);
  }

  f32x16 o0 = zero16(), o1 = zero16();
  float m = -1e30f, lsum = 0.f;

  int srow = lane >> 3;
  int sg8 = ((lane & 7) ^ srow) * 8;

  auto STAGE = [&](int buf, int t0) {
#pragma unroll
    for (int qi = 0; qi < 4; qi++) {
      int chunk = wid * 4 + qi;
      int row = chunk * 8 + srow;
      gll16(Kp + (size_t)(t0 + row) * 64 + sg8, &Kl[buf][chunk * 512]);
      gll16(Vp + (size_t)row * 2048 + t0 + sg8, &Vl[buf][chunk * 512]);
    }
  };

  STAGE(0, 0);

  int r0 = q5, r1 = 32 + q5;
  int sw0 = (r0 & 7), sw1 = (r1 & 7);  // equal, kept for clarity

  for (int t = 0; t < 32; ++t) {
    int cur = t & 1;
    if (t < 31) {
      STAGE(cur ^ 1, (t + 1) * 64);
      asm volatile("s_waitcnt vmcnt(8)" ::: "memory");
    } else {
      asm volatile("s_waitcnt vmcnt(0)" ::: "memory");
    }
    __builtin_amdgcn_s_barrier();

    const f16* kb = Kl[cur];
    const f16* vb = Vl[cur];

    // QK^T: S^T[kv][q] = mfma(A=K rows kv, B=Q cols q), k = d (4 slices of 16)
    f32x16 s0 = zero16(), s1 = zero16();
#pragma unroll
    for (int ks = 0; ks < 4; ks++) {
      int g = 2 * ks + hi;
      f16x8 k0 = *(const f16x8*)(kb + r0 * 64 + ((g ^ sw0) << 3));
      f16x8 k1 = *(const f16x8*)(kb + r1 * 64 + ((g ^ sw1) << 3));
      f16x8 qv = (ks == 0) ? qf0 : (ks == 1) ? qf1 : (ks == 2) ? qf2 : qf3;
      s0 = mfma32(k0, qv, s0);
      s1 = mfma32(k1, qv, s1);
    }

    // lane-local online softmax for column q (halves exchanged at lane^32)
    float mx = s0[0];
#pragma unroll
    for (int i = 1; i < 16; i++) mx = fmaxf(mx, s0[i]);
#pragma unroll
    for (int i = 0; i < 16; i++) mx = fmaxf(mx, s1[i]);
    mx = fmaxf(mx, __shfl_xor(mx, 32));
    float mn = fmaxf(m, mx);
    float al = __expf(m - mn);
    m = mn;
    float sum = 0.f;
#pragma unroll
    for (int i = 0; i < 16; i++) { s0[i] = __expf(s0[i] - mn); sum += s0[i]; }
#pragma unroll
    for (int i = 0; i < 16; i++) { s1[i] = __expf(s1[i] - mn); sum += s1[i]; }
    sum += __shfl_xor(sum, 32);
    lsum = lsum * al + sum;
#pragma unroll
    for (int i = 0; i < 16; i++) { o0[i] *= al; o1[i] *= al; }

    // P -> B-operand fragments (in-register)
    f16x8 pb0 = mk_bfrag(s0[0], s0[1], s0[2], s0[3], s0[4], s0[5], s0[6], s0[7]);
    f16x8 pb1 = mk_bfrag(s0[8], s0[9], s0[10], s0[11], s0[12], s0[13], s0[14], s0[15]);
    f16x8 pb2 = mk_bfrag(s1[0], s1[1], s1[2], s1[3], s1[4], s1[5], s1[6], s1[7]);
    f16x8 pb3 = mk_bfrag(s1[8], s1[9], s1[10], s1[11], s1[12], s1[13], s1[14], s1[15]);

    // PV: O^T[d][q] += mfma(A=V^T rows d, B=P^T cols q), k = kv (4 slices)
#pragma unroll
    for (int ks = 0; ks < 4; ks++) {
      int g = 2 * ks + hi;
      f16x8 v0 = *(const f16x8*)(vb + r0 * 64 + ((g ^ sw0) << 3));
      f16x8 v1 = *(const f16x8*)(vb + r1 * 64 + ((g ^ sw1) << 3));
      f16x8 pv = (ks == 0) ? pb0 : (ks == 1) ? pb1 : (ks == 2) ? pb2 : pb3;
      o0 = mfma32(v0, pv, o0);
      o1 = mfma32(v1, pv, o1);
    }

    asm volatile("" ::: "memory");
    __builtin_amdgcn_s_barrier();
  }

  // epilogue: Oh[b*2048+q][h*64+d] = O^T[d][q] / l
  float inv = 1.f / lsum;
  int b = bh >> 4, h = bh & 15;
  f16* op = Oh + ((size_t)(b * 2048 + q0w + q5)) * 1024 + h * 64;
#pragma unroll
  for (int qd = 0; qd < 4; qd++) {
    f16x4 w0, w1;
#pragma unroll
    for (int j = 0; j < 4; j++) {
      int r = qd * 4 + j;
      w0[j] = (f16)(o0[r] * inv);
      w1[j] = (f16)(o1[r] * inv);
    }
    int d0 = 8 * qd + 4 * hi;
    *(f16x4*)(op + d0) = w0;
    *(f16x4*)(op + 32 + d0) = w1;
  }
}

// ---------------- launch ----------------

extern "C" void kernel_launch(void* const* d_in, const int* in_sizes, int n_in,
                              void* d_out, int out_size, void* d_ws, size_t ws_size,
                              hipStream_t stream) {
  const float* x  = (const float*)d_in[0];
  const float* Wq = (const float*)d_in[1];
  const float* bq = (const float*)d_in[2];
  const float* Wk = (const float*)d_in[3];
  const float* bk = (const float*)d_in[4];
  const float* Wv = (const float*)d_in[5];
  const float* bv = (const float*)d_in[6];
  const float* Wo = (const float*)d_in[7];
  const float* bo = (const float*)d_in[8];
  float* out = (float*)d_out;

  char* ws = (char*)d_ws;
  const size_t MB8 = (size_t)8 << 20;
  f16* Xh = (f16*)(ws + 0 * MB8);
  f16* Wt = (f16*)(ws + 1 * MB8);
  f16* Q  = (f16*)(ws + 2 * MB8);
  f16* Kb = (f16*)(ws + 3 * MB8);
  f16* Vt = (f16*)(ws + 4 * MB8);  // V^T [bh][64][2048]
  f16* Oh = (f16*)(ws + 5 * MB8);

  pack_x_k<<<dim3(2048), dim3(256), 0, stream>>>(x, Xh, 4096 * 1024);
  pack_w_k<<<dim3(16, 16, 4), dim3(256), 0, stream>>>(Wq, Wk, Wv, Wo, Wt);
  gemm_qkv_k<<<dim3(24, 32), dim3(256), 0, stream>>>(Xh, Wt, bq, bk, bv, Q, Kb, Vt);
  attn_k<<<dim3(1024), dim3(128), 0, stream>>>(Q, Kb, Vt, Oh);
  gemm_out_k<<<dim3(8, 32), dim3(256), 0, stream>>>(Oh, Wt + (size_t)3072 * 1024, bo, out);
}